// Round 1
// baseline (304.911 us; speedup 1.0000x reference)
//
#include <hip/hip_runtime.h>
#include <math.h>

// Problem constants: B=32, O=4096, F=256, H=8, HID=128
#define MB_ 131072
#define F_  256
#define HID_ 128
#define H_  8
#define O_  4096
#define B_  32

typedef __attribute__((ext_vector_type(8))) short short8;
typedef __attribute__((ext_vector_type(4))) float f32x4;

static __device__ __forceinline__ unsigned short f2bf(float f) {
    unsigned int u = __float_as_uint(f);
    unsigned int r = (u + 0x7fffu + ((u >> 16) & 1u)) >> 16;  // RNE
    return (unsigned short)r;
}
static __device__ __forceinline__ float bflo(unsigned int u) {
    return __uint_as_float(u << 16);
}
static __device__ __forceinline__ float bfhi(unsigned int u) {
    return __uint_as_float(u & 0xffff0000u);
}
// order-preserving float->uint key for atomicMax
static __device__ __forceinline__ unsigned int fkey(float f) {
    unsigned int u = __float_as_uint(f);
    return (u & 0x80000000u) ? ~u : (u | 0x80000000u);
}

// ---------------- Prep: transpose + bf16-cast weights, init Mmax ------------
__global__ __launch_bounds__(256) void k_prep(
    const float* __restrict__ W_in, const float* __restrict__ W_blk,
    unsigned short* __restrict__ WinT, unsigned short* __restrict__ WblkT,
    unsigned int* __restrict__ Mmax)
{
    const int idx = blockIdx.x * 256 + threadIdx.x;
    if (idx < 256) Mmax[idx] = 0u;  // key-space -inf
    if (idx < 32768) {
        const int n = idx >> 8, k = idx & 255;
        WinT[idx] = f2bf(W_in[(size_t)k * HID_ + n]);
    } else {
        const int i2 = idx - 32768;  // < 16384
        const int n = i2 >> 7, k = i2 & 127;
        WblkT[i2] = f2bf(W_blk[(size_t)k * HID_ + n]);
    }
}

// ---------------- Fused GEMM1+GEMM2 -----------------------------------------
// GEMM1: h = relu(x @ W_in + b_in) (tile 128x128, K=256)
// GEMM2: z = h @ W_blk + b_blk     (K=128, A from LDS h-tile, B from L2)
// + row mask partials + BN partial sums.
// grid 1024, block 256 (4 waves).
__global__ __launch_bounds__(256) void k_fused(
    const float* __restrict__ x, const unsigned short* __restrict__ WinT,
    const float* __restrict__ b_in,
    const unsigned short* __restrict__ WblkT, const float* __restrict__ b_blk,
    unsigned short* __restrict__ h_out, unsigned short* __restrict__ z_out,
    float* __restrict__ mask_out,
    float* __restrict__ sumP, float* __restrict__ sumsqP)
{
    // union: [a_s 128x40 | b_s 128x40] during GEMM1; h_s 128x136 afterwards
    __shared__ unsigned short smem[128 * 136];
    __shared__ float msum_s[128];
    __shared__ float csum_s[128], csumsq_s[128];
    unsigned short* a_s = smem;
    unsigned short* b_s = smem + 5120;

    const int tid = threadIdx.x;
    const int R0 = blockIdx.x * 128;
    const int lp_r = tid >> 3;   // 0..31
    const int lp_c = tid & 7;    // 0..7 (float4 chunk)
    const int wave = tid >> 6;
    const int wrow = wave >> 1, wcol = wave & 1;
    const int lane = tid & 63;
    const int lm = lane & 15, quad = lane >> 4;

    if (tid < 128) { msum_s[tid] = 0.f; csum_s[tid] = 0.f; csumsq_s[tid] = 0.f; }
    float ms[4] = {0.f, 0.f, 0.f, 0.f};

    f32x4 acc[4][4];
#pragma unroll
    for (int i = 0; i < 4; i++)
#pragma unroll
        for (int j = 0; j < 4; j++) acc[i][j] = (f32x4){0.f, 0.f, 0.f, 0.f};

    // ---- GEMM1 main loop ----
    for (int kt = 0; kt < 8; kt++) {
#pragma unroll
        for (int p = 0; p < 4; p++) {
            const int r = lp_r + 32 * p;
            const float4 v = *(const float4*)(x + (size_t)(R0 + r) * F_ + kt * 32 + lp_c * 4);
            ms[p] += v.x * v.x + v.y * v.y + v.z * v.z + v.w * v.w;
            ushort4 o;
            o.x = f2bf(v.x); o.y = f2bf(v.y); o.z = f2bf(v.z); o.w = f2bf(v.w);
            *(ushort4*)(&a_s[r * 40 + lp_c * 4]) = o;
        }
#pragma unroll
        for (int p = 0; p < 4; p++) {
            const int n = lp_r + 32 * p;
            const ushort4 wv = *(const ushort4*)(WinT + (size_t)n * F_ + kt * 32 + lp_c * 4);
            *(ushort4*)(&b_s[n * 40 + lp_c * 4]) = wv;
        }
        __syncthreads();
        short8 af[4], bfr[4];
#pragma unroll
        for (int mi = 0; mi < 4; mi++)
            af[mi] = *(const short8*)(&a_s[(wrow * 64 + mi * 16 + lm) * 40 + quad * 8]);
#pragma unroll
        for (int ni = 0; ni < 4; ni++)
            bfr[ni] = *(const short8*)(&b_s[(wcol * 64 + ni * 16 + lm) * 40 + quad * 8]);
#pragma unroll
        for (int mi = 0; mi < 4; mi++)
#pragma unroll
            for (int ni = 0; ni < 4; ni++)
                acc[mi][ni] = __builtin_amdgcn_mfma_f32_16x16x32_bf16(af[mi], bfr[ni], acc[mi][ni], 0, 0, 0);
        __syncthreads();
    }

    // row-mask partials (LDS atomics, barrier later)
#pragma unroll
    for (int p = 0; p < 4; p++) atomicAdd(&msum_s[lp_r + 32 * p], ms[p]);

    // ---- epilogue 1: bias + relu, write h to global AND to LDS h-tile ----
    {
        float bcol[4];
#pragma unroll
        for (int ni = 0; ni < 4; ni++) bcol[ni] = b_in[wcol * 64 + ni * 16 + lm];
#pragma unroll
        for (int mi = 0; mi < 4; mi++)
#pragma unroll
            for (int r = 0; r < 4; r++) {
                const int rl = wrow * 64 + mi * 16 + quad * 4 + r;
                const size_t grow = (size_t)(R0 + rl) * HID_;
#pragma unroll
                for (int ni = 0; ni < 4; ni++) {
                    const int col = wcol * 64 + ni * 16 + lm;
                    const float v = fmaxf(acc[mi][ni][r] + bcol[ni], 0.f);
                    const unsigned short us = f2bf(v);
                    h_out[grow + col] = us;
                    smem[rl * 136 + col] = us;   // h_s, stride 136 (pad 8)
                }
            }
    }
#pragma unroll
    for (int i = 0; i < 4; i++)
#pragma unroll
        for (int j = 0; j < 4; j++) acc[i][j] = (f32x4){0.f, 0.f, 0.f, 0.f};
    __syncthreads();   // h_s complete, msum complete

    if (tid < 128) mask_out[R0 + tid] = (msum_s[tid] != 0.f) ? 1.f : 0.f;

    // ---- GEMM2: A from h_s (LDS), B from WblkT (global, L2-hot) ----
#pragma unroll
    for (int kt = 0; kt < 4; kt++) {
        short8 af[4], bfr[4];
#pragma unroll
        for (int mi = 0; mi < 4; mi++)
            af[mi] = *(const short8*)(&smem[(wrow * 64 + mi * 16 + lm) * 136 + kt * 32 + quad * 8]);
#pragma unroll
        for (int ni = 0; ni < 4; ni++)
            bfr[ni] = *(const short8*)(WblkT + (size_t)(wcol * 64 + ni * 16 + lm) * HID_ + kt * 32 + quad * 8);
#pragma unroll
        for (int mi = 0; mi < 4; mi++)
#pragma unroll
            for (int ni = 0; ni < 4; ni++)
                acc[mi][ni] = __builtin_amdgcn_mfma_f32_16x16x32_bf16(af[mi], bfr[ni], acc[mi][ni], 0, 0, 0);
    }

    // ---- epilogue 2: bias, BN partials, z store ----
    float bcol2[4];
#pragma unroll
    for (int ni = 0; ni < 4; ni++) bcol2[ni] = b_blk[wcol * 64 + ni * 16 + lm];
    float s_c[4] = {0.f, 0.f, 0.f, 0.f}, ss_c[4] = {0.f, 0.f, 0.f, 0.f};
#pragma unroll
    for (int mi = 0; mi < 4; mi++)
#pragma unroll
        for (int r = 0; r < 4; r++) {
            const size_t row = (size_t)R0 + wrow * 64 + mi * 16 + quad * 4 + r;
#pragma unroll
            for (int ni = 0; ni < 4; ni++) {
                const float zv = acc[mi][ni][r] + bcol2[ni];
                s_c[ni] += zv;
                ss_c[ni] += zv * zv;
                z_out[row * HID_ + wcol * 64 + ni * 16 + lm] = f2bf(zv);
            }
        }
#pragma unroll
    for (int ni = 0; ni < 4; ni++) {
        atomicAdd(&csum_s[wcol * 64 + ni * 16 + lm], s_c[ni]);
        atomicAdd(&csumsq_s[wcol * 64 + ni * 16 + lm], ss_c[ni]);
    }
    __syncthreads();
    if (tid < 128) {
        sumP[(size_t)blockIdx.x * 128 + tid] = csum_s[tid];
        sumsqP[(size_t)blockIdx.x * 128 + tid] = csumsq_s[tid];
    }
}

// ---------------- BN finalize ----------------------------------------------
__global__ __launch_bounds__(256) void k_bnfin(
    const float* __restrict__ sumP, const float* __restrict__ sumsqP,
    const float* __restrict__ gamma, const float* __restrict__ beta,
    float* __restrict__ scale, float* __restrict__ shift)
{
    const int c = blockIdx.x;
    const int tid = threadIdx.x;
    float s = 0.f, ss = 0.f;
    for (int i = tid; i < 1024; i += 256) {
        s  += sumP[(size_t)i * 128 + c];
        ss += sumsqP[(size_t)i * 128 + c];
    }
#pragma unroll
    for (int off = 32; off; off >>= 1) {
        s  += __shfl_xor(s, off, 64);
        ss += __shfl_xor(ss, off, 64);
    }
    __shared__ float rs[4], rss[4];
    const int wid = tid >> 6, lane = tid & 63;
    if (lane == 0) { rs[wid] = s; rss[wid] = ss; }
    __syncthreads();
    if (tid == 0) {
        const float S  = rs[0] + rs[1] + rs[2] + rs[3];
        const float SS = rss[0] + rss[1] + rss[2] + rss[3];
        const float inv_m = 1.0f / (float)MB_;
        const float mu = S * inv_m;
        const float var = SS * inv_m - mu * mu;
        const float sc = gamma[c] * rsqrtf(var + 1e-5f);
        scale[c] = sc;
        shift[c] = beta[c] - mu * sc;
    }
}

// ---------------- logits + gumbel + per-(b,h) max ---------------------------
// grid 256, block 256, 2 rows/thread. Broadcast float4 LDS reads for W_fc.
__global__ __launch_bounds__(256) void k_logits(
    const unsigned short* __restrict__ h_in, const unsigned short* __restrict__ z_in,
    const float* __restrict__ scale, const float* __restrict__ shift,
    const float* __restrict__ W_fc, const float* __restrict__ b_fc,
    const float* __restrict__ mask, const float* __restrict__ gumbel,
    float* __restrict__ t_out, unsigned int* __restrict__ Mmax)
{
    __shared__ float wfc_s[1024];
    __shared__ float sc_s[128], sh_s[128];
    const int tid = threadIdx.x;
    for (int i = tid; i < 1024; i += 256) wfc_s[i] = W_fc[i];
    if (tid < 128) { sc_s[tid] = scale[tid]; sh_s[tid] = shift[tid]; }
    __syncthreads();

    const size_t row0 = (size_t)blockIdx.x * 512 + tid;
    const size_t row1 = row0 + 256;
    float a0[8], a1[8];
#pragma unroll
    for (int j = 0; j < 8; j++) { a0[j] = 0.f; a1[j] = 0.f; }

    const uint4* hp0 = (const uint4*)(h_in + row0 * HID_);
    const uint4* zq0 = (const uint4*)(z_in + row0 * HID_);
    const uint4* hp1 = (const uint4*)(h_in + row1 * HID_);
    const uint4* zq1 = (const uint4*)(z_in + row1 * HID_);

#pragma unroll 2
    for (int kc = 0; kc < 16; kc++) {
        const uint4 h0 = hp0[kc], z0 = zq0[kc];
        const uint4 h1 = hp1[kc], z1 = zq1[kc];
        const unsigned int hs0[4] = {h0.x, h0.y, h0.z, h0.w};
        const unsigned int zs0[4] = {z0.x, z0.y, z0.z, z0.w};
        const unsigned int hs1[4] = {h1.x, h1.y, h1.z, h1.w};
        const unsigned int zs1[4] = {z1.x, z1.y, z1.z, z1.w};
#pragma unroll
        for (int p = 0; p < 4; p++) {
            const int k = kc * 8 + p * 2;
            const float sck0 = sc_s[k], shk0 = sh_s[k];
            const float sck1 = sc_s[k + 1], shk1 = sh_s[k + 1];
            const float4 wA = *(const float4*)&wfc_s[k * 8];        // row k, j0..3
            const float4 wB = *(const float4*)&wfc_s[k * 8 + 4];    // row k, j4..7
            const float4 wC = *(const float4*)&wfc_s[k * 8 + 8];    // row k+1, j0..3
            const float4 wD = *(const float4*)&wfc_s[k * 8 + 12];   // row k+1, j4..7
            {
                const float hf0 = bflo(hs0[p]), hf1 = bfhi(hs0[p]);
                const float zf0 = bflo(zs0[p]), zf1 = bfhi(zs0[p]);
                const float hb0 = fmaxf(zf0 * sck0 + shk0, 0.f) + hf0;
                const float hb1 = fmaxf(zf1 * sck1 + shk1, 0.f) + hf1;
                a0[0] += hb0 * wA.x + hb1 * wC.x;  a0[1] += hb0 * wA.y + hb1 * wC.y;
                a0[2] += hb0 * wA.z + hb1 * wC.z;  a0[3] += hb0 * wA.w + hb1 * wC.w;
                a0[4] += hb0 * wB.x + hb1 * wD.x;  a0[5] += hb0 * wB.y + hb1 * wD.y;
                a0[6] += hb0 * wB.z + hb1 * wD.z;  a0[7] += hb0 * wB.w + hb1 * wD.w;
            }
            {
                const float hf0 = bflo(hs1[p]), hf1 = bfhi(hs1[p]);
                const float zf0 = bflo(zs1[p]), zf1 = bfhi(zs1[p]);
                const float hb0 = fmaxf(zf0 * sck0 + shk0, 0.f) + hf0;
                const float hb1 = fmaxf(zf1 * sck1 + shk1, 0.f) + hf1;
                a1[0] += hb0 * wA.x + hb1 * wC.x;  a1[1] += hb0 * wA.y + hb1 * wC.y;
                a1[2] += hb0 * wA.z + hb1 * wC.z;  a1[3] += hb0 * wA.w + hb1 * wC.w;
                a1[4] += hb0 * wB.x + hb1 * wD.x;  a1[5] += hb0 * wB.y + hb1 * wD.y;
                a1[6] += hb0 * wB.z + hb1 * wD.z;  a1[7] += hb0 * wB.w + hb1 * wD.w;
            }
        }
    }

    float bf[8];
#pragma unroll
    for (int j = 0; j < 8; j++) bf[j] = b_fc[j];
    const float mk0 = mask[row0], mk1 = mask[row1];
    float g0[8], g1[8];
    *(float4*)&g0[0] = *(const float4*)(gumbel + row0 * 8);
    *(float4*)&g0[4] = *(const float4*)(gumbel + row0 * 8 + 4);
    *(float4*)&g1[0] = *(const float4*)(gumbel + row1 * 8);
    *(float4*)&g1[4] = *(const float4*)(gumbel + row1 * 8 + 4);
    float t0[8], t1[8];
#pragma unroll
    for (int j = 0; j < 8; j++) {
        t0[j] = (a0[j] + bf[j]) * mk0 + g0[j];
        t1[j] = (a1[j] + bf[j]) * mk1 + g1[j];
    }
    *(float4*)(t_out + row0 * 8)     = *(float4*)&t0[0];
    *(float4*)(t_out + row0 * 8 + 4) = *(float4*)&t0[4];
    *(float4*)(t_out + row1 * 8)     = *(float4*)&t1[0];
    *(float4*)(t_out + row1 * 8 + 4) = *(float4*)&t1[4];

    // per-(b,h) max partial → atomicMax with order-preserving key
    float tm[8];
#pragma unroll
    for (int j = 0; j < 8; j++) tm[j] = fmaxf(t0[j], t1[j]);
#pragma unroll
    for (int off = 32; off; off >>= 1)
#pragma unroll
        for (int j = 0; j < 8; j++) tm[j] = fmaxf(tm[j], __shfl_xor(tm[j], off, 64));
    if ((tid & 63) == 0) {
        const int bb = blockIdx.x >> 3;   // 512 rows per block, 4096 per b
#pragma unroll
        for (int j = 0; j < 8; j++) atomicMax(&Mmax[bb * 8 + j], fkey(tm[j]));
    }
}

// ---------------- pool: e=exp(t-M) on the fly, unnormalized wsum + Z --------
// grid (64, 32): 64-row o-chunks x batch. 8 blocks/CU.
__global__ __launch_bounds__(256) void k_pool(
    const float* __restrict__ x, const float* __restrict__ t_in,
    const unsigned int* __restrict__ Mmax,
    float* __restrict__ pp, float* __restrict__ zp)
{
    __shared__ float ws_s[8][64];
    __shared__ float M_s[8];
    const int tid = threadIdx.x;
    const int oc = blockIdx.x;
    const int b  = blockIdx.y;
    if (tid < 8) {
        const unsigned int k = Mmax[b * 8 + tid];
        const unsigned int s = (k & 0x80000000u) ? (k & 0x7fffffffu) : ~k;
        M_s[tid] = __uint_as_float(s);
    }
    __syncthreads();
#pragma unroll
    for (int i = tid; i < 512; i += 256) {
        const int ol = i >> 3, hh = i & 7;
        const float tv = t_in[((size_t)b * O_ + oc * 64 + ol) * H_ + hh];
        ws_s[hh][ol] = __expf(tv - M_s[hh]);
    }
    __syncthreads();
    if (tid < 8) {
        float s = 0.f;
        for (int o = 0; o < 64; o++) s += ws_s[tid][o];
        zp[((size_t)oc * 32 + b) * 8 + tid] = s;
    }
    float acc[8];
#pragma unroll
    for (int hh = 0; hh < 8; hh++) acc[hh] = 0.f;
    const float* xp = x + ((size_t)b * O_ + oc * 64) * F_ + tid;
#pragma unroll 4
    for (int o = 0; o < 64; o++) {
        const float xv = xp[(size_t)o * F_];
#pragma unroll
        for (int hh = 0; hh < 8; hh++) acc[hh] += ws_s[hh][o] * xv;
    }
    float* outp = pp + ((size_t)oc * 32 + b) * 2048;
#pragma unroll
    for (int hh = 0; hh < 8; hh++) outp[hh * 256 + tid] = acc[hh];
}

// ---------------- reduce partials + divide by Z -----------------------------
// grid 256 = (b,h); block 256 = f
__global__ __launch_bounds__(256) void k_reduce(
    const float* __restrict__ pp, const float* __restrict__ zp,
    float* __restrict__ out)
{
    const int blk = blockIdx.x;
    const int b = blk >> 3, hh = blk & 7;
    const int tid = threadIdx.x;
    __shared__ float invZ_s;
    if (tid < 64) {
        float z = zp[((size_t)tid * 32 + b) * 8 + hh];
#pragma unroll
        for (int off = 32; off; off >>= 1) z += __shfl_xor(z, off, 64);
        if (tid == 0) invZ_s = 1.f / z;
    }
    __syncthreads();
    float s = 0.f;
    const float* p0 = pp + (size_t)b * 2048 + hh * 256 + tid;
#pragma unroll 8
    for (int ocq = 0; ocq < 64; ocq++) s += p0[(size_t)ocq * 65536];
    out[(size_t)b * 2048 + hh * 256 + tid] = s * invZ_s;
}

extern "C" void kernel_launch(void* const* d_in, const int* in_sizes, int n_in,
                              void* d_out, int out_size, void* d_ws, size_t ws_size,
                              hipStream_t stream)
{
    const float* x      = (const float*)d_in[0];
    const float* gumbel = (const float*)d_in[1];
    const float* W_in   = (const float*)d_in[2];
    const float* b_in   = (const float*)d_in[3];
    const float* W_blk  = (const float*)d_in[4];
    const float* b_blk  = (const float*)d_in[5];
    const float* gamma  = (const float*)d_in[6];
    const float* beta   = (const float*)d_in[7];
    const float* W_fc   = (const float*)d_in[8];
    const float* b_fc   = (const float*)d_in[9];
    float* out = (float*)d_out;
    char* ws = (char*)d_ws;

    // layout (pp/zp alias the h region: h dead after k_logits, pool runs after)
    unsigned short* h_bf  = (unsigned short*)(ws + 0);            // 33554432
    float* pp     = (float*)(ws + 0);                              // 16777216 (alias)
    float* zp     = (float*)(ws + 16777216);                       // 65536    (alias)
    unsigned short* z_bf  = (unsigned short*)(ws + 33554432);      // 33554432
    float* mask   = (float*)(ws + 67108864);                       // 524288
    float* sumP   = (float*)(ws + 67633152);                       // 524288
    float* sumsqP = (float*)(ws + 68157440);                       // 524288
    float* scale  = (float*)(ws + 68681728);                       // 512
    float* shift  = (float*)(ws + 68682240);                       // 512
    float* t_buf  = (float*)(ws + 68682752);                       // 4194304
    unsigned int* Mmax = (unsigned int*)(ws + 72877056);           // 1024
    unsigned short* WinT  = (unsigned short*)(ws + 72878080);      // 65536
    unsigned short* WblkT = (unsigned short*)(ws + 72943616);      // 32768
    // end: 72976384 bytes

    k_prep<<<192, 256, 0, stream>>>(W_in, W_blk, WinT, WblkT, Mmax);
    k_fused<<<1024, 256, 0, stream>>>(x, WinT, b_in, WblkT, b_blk, h_bf, z_bf, mask, sumP, sumsqP);
    k_bnfin<<<128, 256, 0, stream>>>(sumP, sumsqP, gamma, beta, scale, shift);
    k_logits<<<256, 256, 0, stream>>>(h_bf, z_bf, scale, shift, W_fc, b_fc, mask, gumbel, t_buf, Mmax);
    k_pool<<<dim3(64, 32), 256, 0, stream>>>(x, t_buf, Mmax, pp, zp);
    k_reduce<<<256, 256, 0, stream>>>(pp, zp, out);
}

// Round 2
// 303.637 us; speedup vs baseline: 1.0042x; 1.0042x over previous
//
#include <hip/hip_runtime.h>
#include <math.h>

// Problem constants: B=32, O=4096, F=256, H=8, HID=128
#define MB_ 131072
#define F_  256
#define HID_ 128
#define H_  8
#define O_  4096
#define B_  32

typedef __attribute__((ext_vector_type(8))) short short8;
typedef __attribute__((ext_vector_type(4))) float f32x4;

static __device__ __forceinline__ unsigned short f2bf(float f) {
    unsigned int u = __float_as_uint(f);
    unsigned int r = (u + 0x7fffu + ((u >> 16) & 1u)) >> 16;  // RNE
    return (unsigned short)r;
}
static __device__ __forceinline__ float bflo(unsigned int u) {
    return __uint_as_float(u << 16);
}
static __device__ __forceinline__ float bfhi(unsigned int u) {
    return __uint_as_float(u & 0xffff0000u);
}
// order-preserving float->uint key for atomicMax
static __device__ __forceinline__ unsigned int fkey(float f) {
    unsigned int u = __float_as_uint(f);
    return (u & 0x80000000u) ? ~u : (u | 0x80000000u);
}

// ---------------- Prep: transpose + bf16-cast weights, init Mmax ------------
__global__ __launch_bounds__(256) void k_prep(
    const float* __restrict__ W_in, const float* __restrict__ W_blk,
    unsigned short* __restrict__ WinT, unsigned short* __restrict__ WblkT,
    unsigned int* __restrict__ Mmax)
{
    const int idx = blockIdx.x * 256 + threadIdx.x;
    if (idx < 256) Mmax[idx] = 0u;  // key-space -inf
    if (idx < 32768) {
        const int n = idx >> 8, k = idx & 255;
        WinT[idx] = f2bf(W_in[(size_t)k * HID_ + n]);
    } else {
        const int i2 = idx - 32768;  // < 16384
        const int n = i2 >> 7, k = i2 & 127;
        WblkT[i2] = f2bf(W_blk[(size_t)k * HID_ + n]);
    }
}

// ---------------- Fused GEMM1+GEMM2, 8-wave pipelined -----------------------
// GEMM1: h = relu(x @ W_in + b_in) (tile 128x128, K=256, BK=64)
// GEMM2: z = h @ W_blk + b_blk     (K=128, A from LDS h-tile, B regs from L2)
// Wave grid 2x4: per-wave 64x32 output. Loads for kt+1 issued right after
// barrier A of kt so they overlap fragreads+MFMA and drain at barrier B.
__global__ __launch_bounds__(512, 4) void k_fused(
    const float* __restrict__ x, const unsigned short* __restrict__ WinT,
    const float* __restrict__ b_in,
    const unsigned short* __restrict__ WblkT, const float* __restrict__ b_blk,
    unsigned short* __restrict__ h_out, unsigned short* __restrict__ z_out,
    float* __restrict__ mask_out,
    float* __restrict__ sumP, float* __restrict__ sumsqP)
{
    // staging: a_s 128x72 | b_s 128x72 (ushort). h_s (128x136) overlays both.
    __shared__ unsigned short smem[128 * 144];
    __shared__ float msum_s[128];
    __shared__ float csum_s[128], csumsq_s[128];
    unsigned short* a_s = smem;
    unsigned short* b_s = smem + 128 * 72;

    const int tid = threadIdx.x;
    const int R0 = blockIdx.x * 128;
    const int sr = tid >> 2;     // 0..127 staging row
    const int sc = tid & 3;      // 0..3
    const int wave = tid >> 6;   // 0..7
    const int wrow = wave >> 2;  // 0..1
    const int wcol = wave & 3;   // 0..3
    const int lane = tid & 63;
    const int lm = lane & 15, quad = lane >> 4;

    if (tid < 128) { msum_s[tid] = 0.f; csum_s[tid] = 0.f; csumsq_s[tid] = 0.f; }
    float ms = 0.f;

    f32x4 acc[4][2];
#pragma unroll
    for (int i = 0; i < 4; i++)
#pragma unroll
        for (int j = 0; j < 2; j++) acc[i][j] = (f32x4){0.f, 0.f, 0.f, 0.f};

    float4 ax[4];
    short8 bxr[2];
    // prologue loads (kt = 0)
#pragma unroll
    for (int q = 0; q < 4; q++)
        ax[q] = *(const float4*)(x + (size_t)(R0 + sr) * F_ + (q * 4 + sc) * 4);
#pragma unroll
    for (int q = 0; q < 2; q++)
        bxr[q] = *(const short8*)(WinT + (size_t)sr * F_ + (sc + 4 * q) * 8);

    // ---- GEMM1 main loop: 4 K-steps of 64 ----
#pragma unroll
    for (int kt = 0; kt < 4; kt++) {
        // store stage (auto vmcnt wait on ax/bxr)
#pragma unroll
        for (int q = 0; q < 4; q++) {
            const float4 v = ax[q];
            ms += v.x * v.x + v.y * v.y + v.z * v.z + v.w * v.w;
            ushort4 o;
            o.x = f2bf(v.x); o.y = f2bf(v.y); o.z = f2bf(v.z); o.w = f2bf(v.w);
            *(ushort4*)(&a_s[sr * 72 + (q * 4 + sc) * 4]) = o;
        }
#pragma unroll
        for (int q = 0; q < 2; q++)
            *(short8*)(&b_s[sr * 72 + (sc + 4 * q) * 8]) = bxr[q];
        __syncthreads();  // barrier A: tiles(kt) visible

        // issue loads for kt+1: register-only, no LDS hazard; they fly
        // during fragreads+MFMA and drain at barrier B.
        if (kt < 3) {
#pragma unroll
            for (int q = 0; q < 4; q++)
                ax[q] = *(const float4*)(x + (size_t)(R0 + sr) * F_ + (kt + 1) * 64 + (q * 4 + sc) * 4);
#pragma unroll
            for (int q = 0; q < 2; q++)
                bxr[q] = *(const short8*)(WinT + (size_t)sr * F_ + (kt + 1) * 64 + (sc + 4 * q) * 8);
        }

#pragma unroll
        for (int ks = 0; ks < 2; ks++) {
            short8 af[4], bfr[2];
#pragma unroll
            for (int mi = 0; mi < 4; mi++)
                af[mi] = *(const short8*)(&a_s[(wrow * 64 + mi * 16 + lm) * 72 + ks * 32 + quad * 8]);
#pragma unroll
            for (int ni = 0; ni < 2; ni++)
                bfr[ni] = *(const short8*)(&b_s[(wcol * 32 + ni * 16 + lm) * 72 + ks * 32 + quad * 8]);
#pragma unroll
            for (int mi = 0; mi < 4; mi++)
#pragma unroll
                for (int ni = 0; ni < 2; ni++)
                    acc[mi][ni] = __builtin_amdgcn_mfma_f32_16x16x32_bf16(af[mi], bfr[ni], acc[mi][ni], 0, 0, 0);
        }
        __syncthreads();  // barrier B: fragreads done (LDS free), kt+1 loads drained
    }

    // row-mask partials (4 adders per row)
    atomicAdd(&msum_s[sr], ms);

    // prefetch GEMM2 B fragments (WblkT, L2-hot) — overlap with epilogue 1
    short8 wb[4][2];
#pragma unroll
    for (int kt2 = 0; kt2 < 4; kt2++)
#pragma unroll
        for (int ni = 0; ni < 2; ni++)
            wb[kt2][ni] = *(const short8*)(WblkT + (size_t)(wcol * 32 + ni * 16 + lm) * HID_ + kt2 * 32 + quad * 8);

    // ---- epilogue 1: bias + relu, write h to global AND LDS h-tile ----
    {
        float bcol[2];
#pragma unroll
        for (int ni = 0; ni < 2; ni++) bcol[ni] = b_in[wcol * 32 + ni * 16 + lm];
#pragma unroll
        for (int mi = 0; mi < 4; mi++)
#pragma unroll
            for (int r = 0; r < 4; r++) {
                const int rl = wrow * 64 + mi * 16 + quad * 4 + r;
                const size_t grow = (size_t)(R0 + rl) * HID_;
#pragma unroll
                for (int ni = 0; ni < 2; ni++) {
                    const int col = wcol * 32 + ni * 16 + lm;
                    const float v = fmaxf(acc[mi][ni][r] + bcol[ni], 0.f);
                    const unsigned short us = f2bf(v);
                    h_out[grow + col] = us;
                    smem[rl * 136 + col] = us;   // h_s, stride 136
                }
            }
    }
#pragma unroll
    for (int i = 0; i < 4; i++)
#pragma unroll
        for (int j = 0; j < 2; j++) acc[i][j] = (f32x4){0.f, 0.f, 0.f, 0.f};
    __syncthreads();   // h_s complete, msum complete, wb drained

    if (tid < 128) mask_out[R0 + tid] = (msum_s[tid] != 0.f) ? 1.f : 0.f;

    // ---- GEMM2: A from h_s (LDS), B from registers ----
#pragma unroll
    for (int kt2 = 0; kt2 < 4; kt2++) {
        short8 haf[4];
#pragma unroll
        for (int mi = 0; mi < 4; mi++)
            haf[mi] = *(const short8*)(&smem[(wrow * 64 + mi * 16 + lm) * 136 + kt2 * 32 + quad * 8]);
#pragma unroll
        for (int mi = 0; mi < 4; mi++)
#pragma unroll
            for (int ni = 0; ni < 2; ni++)
                acc[mi][ni] = __builtin_amdgcn_mfma_f32_16x16x32_bf16(haf[mi], wb[kt2][ni], acc[mi][ni], 0, 0, 0);
    }

    // ---- epilogue 2: bias, BN partials, z store ----
    float bcol2[2];
#pragma unroll
    for (int ni = 0; ni < 2; ni++) bcol2[ni] = b_blk[wcol * 32 + ni * 16 + lm];
    float s_c[2] = {0.f, 0.f}, ss_c[2] = {0.f, 0.f};
#pragma unroll
    for (int mi = 0; mi < 4; mi++)
#pragma unroll
        for (int r = 0; r < 4; r++) {
            const size_t row = (size_t)R0 + wrow * 64 + mi * 16 + quad * 4 + r;
#pragma unroll
            for (int ni = 0; ni < 2; ni++) {
                const float zv = acc[mi][ni][r] + bcol2[ni];
                s_c[ni] += zv;
                ss_c[ni] += zv * zv;
                z_out[row * HID_ + wcol * 32 + ni * 16 + lm] = f2bf(zv);
            }
        }
#pragma unroll
    for (int ni = 0; ni < 2; ni++) {
        atomicAdd(&csum_s[wcol * 32 + ni * 16 + lm], s_c[ni]);
        atomicAdd(&csumsq_s[wcol * 32 + ni * 16 + lm], ss_c[ni]);
    }
    __syncthreads();
    if (tid < 128) {
        sumP[(size_t)blockIdx.x * 128 + tid] = csum_s[tid];
        sumsqP[(size_t)blockIdx.x * 128 + tid] = csumsq_s[tid];
    }
}

// ---------------- BN finalize ----------------------------------------------
__global__ __launch_bounds__(256) void k_bnfin(
    const float* __restrict__ sumP, const float* __restrict__ sumsqP,
    const float* __restrict__ gamma, const float* __restrict__ beta,
    float* __restrict__ scale, float* __restrict__ shift)
{
    const int c = blockIdx.x;
    const int tid = threadIdx.x;
    float s = 0.f, ss = 0.f;
    for (int i = tid; i < 1024; i += 256) {
        s  += sumP[(size_t)i * 128 + c];
        ss += sumsqP[(size_t)i * 128 + c];
    }
#pragma unroll
    for (int off = 32; off; off >>= 1) {
        s  += __shfl_xor(s, off, 64);
        ss += __shfl_xor(ss, off, 64);
    }
    __shared__ float rs[4], rss[4];
    const int wid = tid >> 6, lane = tid & 63;
    if (lane == 0) { rs[wid] = s; rss[wid] = ss; }
    __syncthreads();
    if (tid == 0) {
        const float S  = rs[0] + rs[1] + rs[2] + rs[3];
        const float SS = rss[0] + rss[1] + rss[2] + rss[3];
        const float inv_m = 1.0f / (float)MB_;
        const float mu = S * inv_m;
        const float var = SS * inv_m - mu * mu;
        const float sc = gamma[c] * rsqrtf(var + 1e-5f);
        scale[c] = sc;
        shift[c] = beta[c] - mu * sc;
    }
}

// ---------------- logits + gumbel + per-(b,h) max ---------------------------
__global__ __launch_bounds__(256) void k_logits(
    const unsigned short* __restrict__ h_in, const unsigned short* __restrict__ z_in,
    const float* __restrict__ scale, const float* __restrict__ shift,
    const float* __restrict__ W_fc, const float* __restrict__ b_fc,
    const float* __restrict__ mask, const float* __restrict__ gumbel,
    float* __restrict__ t_out, unsigned int* __restrict__ Mmax)
{
    __shared__ float wfc_s[1024];
    __shared__ float sc_s[128], sh_s[128];
    const int tid = threadIdx.x;
    for (int i = tid; i < 1024; i += 256) wfc_s[i] = W_fc[i];
    if (tid < 128) { sc_s[tid] = scale[tid]; sh_s[tid] = shift[tid]; }
    __syncthreads();

    const size_t row0 = (size_t)blockIdx.x * 512 + tid;
    const size_t row1 = row0 + 256;
    float a0[8], a1[8];
#pragma unroll
    for (int j = 0; j < 8; j++) { a0[j] = 0.f; a1[j] = 0.f; }

    const uint4* hp0 = (const uint4*)(h_in + row0 * HID_);
    const uint4* zq0 = (const uint4*)(z_in + row0 * HID_);
    const uint4* hp1 = (const uint4*)(h_in + row1 * HID_);
    const uint4* zq1 = (const uint4*)(z_in + row1 * HID_);

#pragma unroll 2
    for (int kc = 0; kc < 16; kc++) {
        const uint4 h0 = hp0[kc], z0 = zq0[kc];
        const uint4 h1 = hp1[kc], z1 = zq1[kc];
        const unsigned int hs0[4] = {h0.x, h0.y, h0.z, h0.w};
        const unsigned int zs0[4] = {z0.x, z0.y, z0.z, z0.w};
        const unsigned int hs1[4] = {h1.x, h1.y, h1.z, h1.w};
        const unsigned int zs1[4] = {z1.x, z1.y, z1.z, z1.w};
#pragma unroll
        for (int p = 0; p < 4; p++) {
            const int k = kc * 8 + p * 2;
            const float sck0 = sc_s[k], shk0 = sh_s[k];
            const float sck1 = sc_s[k + 1], shk1 = sh_s[k + 1];
            const float4 wA = *(const float4*)&wfc_s[k * 8];
            const float4 wB = *(const float4*)&wfc_s[k * 8 + 4];
            const float4 wC = *(const float4*)&wfc_s[k * 8 + 8];
            const float4 wD = *(const float4*)&wfc_s[k * 8 + 12];
            {
                const float hf0 = bflo(hs0[p]), hf1 = bfhi(hs0[p]);
                const float zf0 = bflo(zs0[p]), zf1 = bfhi(zs0[p]);
                const float hb0 = fmaxf(zf0 * sck0 + shk0, 0.f) + hf0;
                const float hb1 = fmaxf(zf1 * sck1 + shk1, 0.f) + hf1;
                a0[0] += hb0 * wA.x + hb1 * wC.x;  a0[1] += hb0 * wA.y + hb1 * wC.y;
                a0[2] += hb0 * wA.z + hb1 * wC.z;  a0[3] += hb0 * wA.w + hb1 * wC.w;
                a0[4] += hb0 * wB.x + hb1 * wD.x;  a0[5] += hb0 * wB.y + hb1 * wD.y;
                a0[6] += hb0 * wB.z + hb1 * wD.z;  a0[7] += hb0 * wB.w + hb1 * wD.w;
            }
            {
                const float hf0 = bflo(hs1[p]), hf1 = bfhi(hs1[p]);
                const float zf0 = bflo(zs1[p]), zf1 = bfhi(zs1[p]);
                const float hb0 = fmaxf(zf0 * sck0 + shk0, 0.f) + hf0;
                const float hb1 = fmaxf(zf1 * sck1 + shk1, 0.f) + hf1;
                a1[0] += hb0 * wA.x + hb1 * wC.x;  a1[1] += hb0 * wA.y + hb1 * wC.y;
                a1[2] += hb0 * wA.z + hb1 * wC.z;  a1[3] += hb0 * wA.w + hb1 * wC.w;
                a1[4] += hb0 * wB.x + hb1 * wD.x;  a1[5] += hb0 * wB.y + hb1 * wD.y;
                a1[6] += hb0 * wB.z + hb1 * wD.z;  a1[7] += hb0 * wB.w + hb1 * wD.w;
            }
        }
    }

    float bf[8];
#pragma unroll
    for (int j = 0; j < 8; j++) bf[j] = b_fc[j];
    const float mk0 = mask[row0], mk1 = mask[row1];
    float g0[8], g1[8];
    *(float4*)&g0[0] = *(const float4*)(gumbel + row0 * 8);
    *(float4*)&g0[4] = *(const float4*)(gumbel + row0 * 8 + 4);
    *(float4*)&g1[0] = *(const float4*)(gumbel + row1 * 8);
    *(float4*)&g1[4] = *(const float4*)(gumbel + row1 * 8 + 4);
    float t0[8], t1[8];
#pragma unroll
    for (int j = 0; j < 8; j++) {
        t0[j] = (a0[j] + bf[j]) * mk0 + g0[j];
        t1[j] = (a1[j] + bf[j]) * mk1 + g1[j];
    }
    *(float4*)(t_out + row0 * 8)     = *(float4*)&t0[0];
    *(float4*)(t_out + row0 * 8 + 4) = *(float4*)&t0[4];
    *(float4*)(t_out + row1 * 8)     = *(float4*)&t1[0];
    *(float4*)(t_out + row1 * 8 + 4) = *(float4*)&t1[4];

    float tm[8];
#pragma unroll
    for (int j = 0; j < 8; j++) tm[j] = fmaxf(t0[j], t1[j]);
#pragma unroll
    for (int off = 32; off; off >>= 1)
#pragma unroll
        for (int j = 0; j < 8; j++) tm[j] = fmaxf(tm[j], __shfl_xor(tm[j], off, 64));
    if ((tid & 63) == 0) {
        const int bb = blockIdx.x >> 3;   // 512 rows per block, 4096 per b
#pragma unroll
        for (int j = 0; j < 8; j++) atomicMax(&Mmax[bb * 8 + j], fkey(tm[j]));
    }
}

// ---------------- pool: e=exp(t-M) on the fly, unnormalized wsum + Z --------
__global__ __launch_bounds__(256) void k_pool(
    const float* __restrict__ x, const float* __restrict__ t_in,
    const unsigned int* __restrict__ Mmax,
    float* __restrict__ pp, float* __restrict__ zp)
{
    __shared__ float ws_s[8][64];
    __shared__ float M_s[8];
    const int tid = threadIdx.x;
    const int oc = blockIdx.x;
    const int b  = blockIdx.y;
    if (tid < 8) {
        const unsigned int k = Mmax[b * 8 + tid];
        const unsigned int s = (k & 0x80000000u) ? (k & 0x7fffffffu) : ~k;
        M_s[tid] = __uint_as_float(s);
    }
    __syncthreads();
#pragma unroll
    for (int i = tid; i < 512; i += 256) {
        const int ol = i >> 3, hh = i & 7;
        const float tv = t_in[((size_t)b * O_ + oc * 64 + ol) * H_ + hh];
        ws_s[hh][ol] = __expf(tv - M_s[hh]);
    }
    __syncthreads();
    if (tid < 8) {
        float s = 0.f;
        for (int o = 0; o < 64; o++) s += ws_s[tid][o];
        zp[((size_t)oc * 32 + b) * 8 + tid] = s;
    }
    float acc[8];
#pragma unroll
    for (int hh = 0; hh < 8; hh++) acc[hh] = 0.f;
    const float* xp = x + ((size_t)b * O_ + oc * 64) * F_ + tid;
#pragma unroll 4
    for (int o = 0; o < 64; o++) {
        const float xv = xp[(size_t)o * F_];
#pragma unroll
        for (int hh = 0; hh < 8; hh++) acc[hh] += ws_s[hh][o] * xv;
    }
    float* outp = pp + ((size_t)oc * 32 + b) * 2048;
#pragma unroll
    for (int hh = 0; hh < 8; hh++) outp[hh * 256 + tid] = acc[hh];
}

// ---------------- reduce partials + divide by Z -----------------------------
__global__ __launch_bounds__(256) void k_reduce(
    const float* __restrict__ pp, const float* __restrict__ zp,
    float* __restrict__ out)
{
    const int blk = blockIdx.x;
    const int b = blk >> 3, hh = blk & 7;
    const int tid = threadIdx.x;
    __shared__ float invZ_s;
    if (tid < 64) {
        float z = zp[((size_t)tid * 32 + b) * 8 + hh];
#pragma unroll
        for (int off = 32; off; off >>= 1) z += __shfl_xor(z, off, 64);
        if (tid == 0) invZ_s = 1.f / z;
    }
    __syncthreads();
    float s = 0.f;
    const float* p0 = pp + (size_t)b * 2048 + hh * 256 + tid;
#pragma unroll 8
    for (int ocq = 0; ocq < 64; ocq++) s += p0[(size_t)ocq * 65536];
    out[(size_t)b * 2048 + hh * 256 + tid] = s * invZ_s;
}

extern "C" void kernel_launch(void* const* d_in, const int* in_sizes, int n_in,
                              void* d_out, int out_size, void* d_ws, size_t ws_size,
                              hipStream_t stream)
{
    const float* x      = (const float*)d_in[0];
    const float* gumbel = (const float*)d_in[1];
    const float* W_in   = (const float*)d_in[2];
    const float* b_in   = (const float*)d_in[3];
    const float* W_blk  = (const float*)d_in[4];
    const float* b_blk  = (const float*)d_in[5];
    const float* gamma  = (const float*)d_in[6];
    const float* beta   = (const float*)d_in[7];
    const float* W_fc   = (const float*)d_in[8];
    const float* b_fc   = (const float*)d_in[9];
    float* out = (float*)d_out;
    char* ws = (char*)d_ws;

    unsigned short* h_bf  = (unsigned short*)(ws + 0);            // 33554432
    float* pp     = (float*)(ws + 0);                              // 16777216 (alias)
    float* zp     = (float*)(ws + 16777216);                       // 65536    (alias)
    unsigned short* z_bf  = (unsigned short*)(ws + 33554432);      // 33554432
    float* mask   = (float*)(ws + 67108864);                       // 524288
    float* sumP   = (float*)(ws + 67633152);                       // 524288
    float* sumsqP = (float*)(ws + 68157440);                       // 524288
    float* scale  = (float*)(ws + 68681728);                       // 512
    float* shift  = (float*)(ws + 68682240);                       // 512
    float* t_buf  = (float*)(ws + 68682752);                       // 4194304
    unsigned int* Mmax = (unsigned int*)(ws + 72877056);           // 1024
    unsigned short* WinT  = (unsigned short*)(ws + 72878080);      // 65536
    unsigned short* WblkT = (unsigned short*)(ws + 72943616);      // 32768

    k_prep<<<192, 256, 0, stream>>>(W_in, W_blk, WinT, WblkT, Mmax);
    k_fused<<<1024, 512, 0, stream>>>(x, WinT, b_in, WblkT, b_blk, h_bf, z_bf, mask, sumP, sumsqP);
    k_bnfin<<<128, 256, 0, stream>>>(sumP, sumsqP, gamma, beta, scale, shift);
    k_logits<<<256, 256, 0, stream>>>(h_bf, z_bf, scale, shift, W_fc, b_fc, mask, gumbel, t_buf, Mmax);
    k_pool<<<dim3(64, 32), 256, 0, stream>>>(x, t_buf, Mmax, pp, zp);
    k_reduce<<<256, 256, 0, stream>>>(pp, zp, out);
}